// Round 5
// baseline (3167.689 us; speedup 1.0000x reference)
//
#include <hip/hip_runtime.h>
#include <hip/hip_bf16.h>

typedef unsigned short ushort_t;
typedef __attribute__((ext_vector_type(4))) float f32x4;
typedef __attribute__((ext_vector_type(8))) short bf16x8;
typedef __attribute__((ext_vector_type(8))) unsigned short us8;

#define T_TOK 4096
#define D_DIM 1024
#define FF_DIM 4096
#define NE 8
#define ESTRIDE 4194304L  // 4096*1024 elements per expert weight matrix

__device__ __forceinline__ unsigned short f2bf(float f) {
  __hip_bfloat16 h = __float2bfloat16(f);
  return __builtin_bit_cast(unsigned short, h);
}
__device__ __forceinline__ float gelu_f(float v) {
  return 0.5f * v * (1.0f + erff(v * 0.70710678118654752440f));
}

// ---------------- gating: logits -> softmax top2 -> expert lists -------------
__global__ void gate_kernel(const float* __restrict__ x, const float* __restrict__ Wg,
                            int* __restrict__ cnt, int* __restrict__ tok,
                            float* __restrict__ wof, int* __restrict__ rankof) {
  const int t = blockIdx.x;
  const int lane = threadIdx.x;  // 64 threads = 1 wave
  const float* xr = x + (long)t * D_DIM;
  float acc[NE];
#pragma unroll
  for (int e = 0; e < NE; e++) acc[e] = 0.f;
#pragma unroll
  for (int i = 0; i < 16; i++) {
    int d = i * 64 + lane;
    float xv = xr[d];
    const float* wr = Wg + d * NE;
#pragma unroll
    for (int e = 0; e < NE; e++) acc[e] += xv * wr[e];
  }
#pragma unroll
  for (int off = 32; off > 0; off >>= 1) {
#pragma unroll
    for (int e = 0; e < NE; e++) acc[e] += __shfl_xor(acc[e], off, 64);
  }
  if (lane == 0) {
    int i0 = 0;
#pragma unroll
    for (int e = 1; e < NE; e++) if (acc[e] > acc[i0]) i0 = e;
    int i1 = -1;
#pragma unroll
    for (int e = 0; e < NE; e++) {
      if (e == i0) continue;
      if (i1 < 0 || acc[e] > acc[i1]) i1 = e;
    }
    float e1 = expf(acc[i1] - acc[i0]);
    float w0 = 1.f / (1.f + e1);
    float w1 = e1 * w0;
    int s0 = atomicAdd(&cnt[i0], 1);
    tok[i0 * T_TOK + s0] = t; wof[i0 * T_TOK + s0] = w0; rankof[i0 * T_TOK + s0] = 0;
    int s1 = atomicAdd(&cnt[i1], 1);
    tok[i1 * T_TOK + s1] = t; wof[i1 * T_TOK + s1] = w1; rankof[i1 * T_TOK + s1] = 1;
    tok[8 * T_TOK + t] = t; wof[8 * T_TOK + t] = 1.f; rankof[8 * T_TOK + t] = 0;
  }
}

__global__ void scan_kernel(int* cnt, int* base) {
  if (threadIdx.x == 0 && blockIdx.x == 0) {
    int s = 0;
    for (int e = 0; e < NE; e++) { base[e] = s; s += cnt[e]; }
    base[8] = s;      // always 8192
    cnt[8] = T_TOK;   // shared pseudo-expert gets all tokens
  }
}

// ---------------- build work-item queues (no dead blocks) -------------------
// q1: GEMM1 items (e, my, nx) nx<32; q2: GEMM2 items nx<8. Ordered (e,my,nx)
// so concurrent blocks share A-panels. nq[0]=|q1|, nq[1]=|q2|.
__global__ void build_queue_kernel(const int* __restrict__ cnt,
                                   unsigned int* __restrict__ q1,
                                   unsigned int* __restrict__ q2,
                                   int* __restrict__ nq) {
  const int e = blockIdx.x;  // 9 blocks
  int off1 = 0, off2 = 0, tot1 = 0, tot2 = 0, mym = 0;
  for (int i = 0; i < 9; i++) {
    int c = (i == 8) ? T_TOK : cnt[i];
    int m = (c + 127) >> 7;
    if (i < e) { off1 += m * 32; off2 += m * 8; }
    if (i == e) mym = m;
    tot1 += m * 32; tot2 += m * 8;
  }
  for (int i = threadIdx.x; i < mym * 32; i += 256) {
    int my = i >> 5, nx = i & 31;
    q1[off1 + i] = ((unsigned)e << 16) | ((unsigned)my << 8) | (unsigned)nx;
  }
  for (int i = threadIdx.x; i < mym * 8; i += 256) {
    int my = i >> 3, nx = i & 7;
    q2[off2 + i] = ((unsigned)e << 16) | ((unsigned)my << 8) | (unsigned)nx;
  }
  if (e == 0 && threadIdx.x == 0) { nq[0] = tot1; nq[1] = tot2; }
}

// ---------------- fp32 -> bf16 convert (x) ----------------------------------
__global__ void cvt_x_kernel(const float* __restrict__ src, ushort_t* __restrict__ dst) {
  long i = ((long)blockIdx.x * 256 + threadIdx.x) * 8;
  float4 v0 = *(const float4*)(src + i);
  float4 v1 = *(const float4*)(src + i + 4);
  us8 o;
  o[0] = f2bf(v0.x); o[1] = f2bf(v0.y); o[2] = f2bf(v0.z); o[3] = f2bf(v0.w);
  o[4] = f2bf(v1.x); o[5] = f2bf(v1.y); o[6] = f2bf(v1.z); o[7] = f2bf(v1.w);
  *(us8*)(dst + i) = o;
}

// ---------------- fp32 [R][C] -> bf16 [C][R] transpose-convert --------------
__global__ void tcvt_kernel(const float* __restrict__ src, ushort_t* __restrict__ dst,
                            int R, int C) {
  src += (long)blockIdx.z * R * C;
  dst += (long)blockIdx.z * R * C;
  const int r0 = blockIdx.y * 64, c0 = blockIdx.x * 64;
  __shared__ ushort_t tile[64][72];
  const int t = threadIdx.x;
#pragma unroll
  for (int i = 0; i < 4; i++) {
    int lin = t + i * 256;
    int r = lin >> 4;
    int c = (lin & 15) * 4;
    float4 v = *(const float4*)(src + (long)(r0 + r) * C + c0 + c);
    tile[c + 0][r] = f2bf(v.x);
    tile[c + 1][r] = f2bf(v.y);
    tile[c + 2][r] = f2bf(v.z);
    tile[c + 3][r] = f2bf(v.w);
  }
  __syncthreads();
#pragma unroll
  for (int i = 0; i < 2; i++) {
    int lin = t + i * 256;
    int cc = lin >> 3, rp = lin & 7;
    us8 v = *(const us8*)&tile[cc][rp * 8];
    *(us8*)(dst + (long)(c0 + cc) * R + r0 + rp * 8) = v;
  }
}

// ---------------- GEMM: persistent blocks, 128x128 tile, 4 waves ------------
// Queue-driven grid-stride over real work items only; simple serial K-loop
// (r1-proven); latency hidden by cross-block wave overlap (target 8 blocks/CU:
// 16 KiB LDS, <=64 VGPR via __launch_bounds__(256,8)).
// PHASE 1: He = gelu(gather(Xbf) @ W1T^T + b1)   (K=1024, N=4096)
// PHASE 2: ybuf/out = route(He @ W2T^T + b2)     (K=4096, N=1024)
template <int K, int N, int PHASE>
__global__ __launch_bounds__(256, 8) void gemm_kernel(
    const ushort_t* __restrict__ Abase, const ushort_t* __restrict__ WT,
    const float* __restrict__ bias_e, const float* __restrict__ bias_s,
    const int* __restrict__ cnt, const int* __restrict__ base,
    const int* __restrict__ tok, const float* __restrict__ wof,
    const int* __restrict__ rankof,
    const unsigned int* __restrict__ q, const int* __restrict__ nq_all,
    ushort_t* __restrict__ He, float* __restrict__ ybuf, float* __restrict__ out) {
  const int nq = nq_all[PHASE - 1];
  const int tid = threadIdx.x;
  const int w = tid >> 6, lane = tid & 63;
  const int wm = w >> 1, wn = w & 1;
  const int lr = lane & 15, lg = lane >> 4;

  __shared__ ushort_t sA[128 * 32];
  __shared__ ushort_t sB[128 * 32];
  const int lds0 = (w * 128) * 16;
  const int lds1 = (w * 128 + 64) * 16;

  for (int it = blockIdx.x; it < nq; it += gridDim.x) {
    const unsigned int item = q[it];
    const int e = item >> 16;
    const int m0 = ((item >> 8) & 0xff) * 128;
    const int n0 = (item & 0xff) * 128;
    const int count = cnt[e];

    // per-item staging pointers: 2 A-chunks + 2 B-chunks (16B each) per K-step
    const ushort_t* pA[2];
    const ushort_t* pB[2];
#pragma unroll
    for (int j = 0; j < 2; j++) {
      int c = w * 128 + j * 64 + lane;  // chunk id in [0,512)
      int r = c >> 2, kp = c & 3;       // tile row, 8-elem k-part
      int rr = m0 + r;
      int rc = (rr < count) ? rr : 0;   // clamp OOB rows
      long arow;
      if (PHASE == 1) arow = tok[e * T_TOK + rc];
      else            arow = (long)base[e] + rc;
      pA[j] = Abase + arow * (long)K + kp * 8;
      pB[j] = WT + (long)e * ESTRIDE + (long)(n0 + r) * K + kp * 8;
    }

    f32x4 acc[4][4] = {};

    for (int k0 = 0; k0 < K; k0 += 32) {
      __builtin_amdgcn_global_load_lds(
          (const __attribute__((address_space(1))) void*)(pA[0] + k0),
          (__attribute__((address_space(3))) void*)((char*)sA + lds0), 16, 0, 0);
      __builtin_amdgcn_global_load_lds(
          (const __attribute__((address_space(1))) void*)(pA[1] + k0),
          (__attribute__((address_space(3))) void*)((char*)sA + lds1), 16, 0, 0);
      __builtin_amdgcn_global_load_lds(
          (const __attribute__((address_space(1))) void*)(pB[0] + k0),
          (__attribute__((address_space(3))) void*)((char*)sB + lds0), 16, 0, 0);
      __builtin_amdgcn_global_load_lds(
          (const __attribute__((address_space(1))) void*)(pB[1] + k0),
          (__attribute__((address_space(3))) void*)((char*)sB + lds1), 16, 0, 0);
      __syncthreads();  // drains vmcnt; staging visible

      bf16x8 av[4], bv[4];
#pragma unroll
      for (int m = 0; m < 4; m++)
        av[m] = *(const bf16x8*)&sA[(wm * 64 + m * 16 + lr) * 32 + lg * 8];
#pragma unroll
      for (int n = 0; n < 4; n++)
        bv[n] = *(const bf16x8*)&sB[(wn * 64 + n * 16 + lr) * 32 + lg * 8];
#pragma unroll
      for (int m = 0; m < 4; m++)
#pragma unroll
        for (int n = 0; n < 4; n++)
          acc[m][n] = __builtin_amdgcn_mfma_f32_16x16x32_bf16(av[m], bv[n], acc[m][n], 0, 0, 0);
      __syncthreads();  // compute done before next stage overwrites LDS
    }

    const float* bias = (e == NE) ? bias_s : (bias_e + (long)e * N);
#pragma unroll
    for (int m = 0; m < 4; m++) {
#pragma unroll
      for (int j = 0; j < 4; j++) {
        int rloc = wm * 64 + m * 16 + lg * 4 + j;  // D row = (lane>>4)*4 + reg
        int rr = m0 + rloc;
        if (rr >= count) continue;
        if (PHASE == 1) {
          long orow = (long)base[e] + rr;
#pragma unroll
          for (int n = 0; n < 4; n++) {
            int col = n0 + wn * 64 + n * 16 + lr;  // D col = lane&15
            float v = acc[m][n][j] + bias[col];
            He[orow * FF_DIM + col] = f2bf(gelu_f(v));
          }
        } else {
          int tt = tok[e * T_TOK + rr];
          if (e == NE) {  // shared FFN -> d_out directly
#pragma unroll
            for (int n = 0; n < 4; n++) {
              int col = n0 + wn * 64 + n * 16 + lr;
              out[(long)tt * D_DIM + col] = acc[m][n][j] + bias[col];
            }
          } else {
            float wgt = wof[e * T_TOK + rr];
            int rk = rankof[e * T_TOK + rr];
            float* dst = ybuf + (long)rk * ((long)T_TOK * D_DIM) + (long)tt * D_DIM;
#pragma unroll
            for (int n = 0; n < 4; n++) {
              int col = n0 + wn * 64 + n * 16 + lr;
              dst[col] = wgt * (acc[m][n][j] + bias[col]);
            }
          }
        }
      }
    }
    // last K-step ended with __syncthreads(); epilogue touches no LDS -> safe
  }
}

// ---------------- final: out += y_rank0 + y_rank1 ---------------------------
__global__ void final_add_kernel(float* __restrict__ out, const float* __restrict__ ybuf) {
  long i = ((long)blockIdx.x * 256 + threadIdx.x) * 4;
  float4 a = *(const float4*)(out + i);
  float4 b = *(const float4*)(ybuf + i);
  float4 c = *(const float4*)(ybuf + (long)T_TOK * D_DIM + i);
  a.x += b.x + c.x; a.y += b.y + c.y; a.z += b.z + c.z; a.w += b.w + c.w;
  *(float4*)(out + i) = a;
}

extern "C" void kernel_launch(void* const* d_in, const int* in_sizes, int n_in,
                              void* d_out, int out_size, void* d_ws, size_t ws_size,
                              hipStream_t stream) {
  (void)in_sizes; (void)n_in; (void)out_size; (void)ws_size;
  const float* x   = (const float*)d_in[0];
  const float* Wg  = (const float*)d_in[1];
  const float* W1  = (const float*)d_in[2];
  const float* b1  = (const float*)d_in[3];
  const float* W2  = (const float*)d_in[4];
  const float* b2  = (const float*)d_in[5];
  const float* Ws1 = (const float*)d_in[6];
  const float* bs1 = (const float*)d_in[7];
  const float* Ws2 = (const float*)d_in[8];
  const float* bs2 = (const float*)d_in[9];
  float* out = (float*)d_out;

  char* ws = (char*)d_ws;
  int*      cnt    = (int*)(ws + 0);
  int*      base   = (int*)(ws + 64);
  int*      tok    = (int*)(ws + 256);
  float*    wof    = (float*)(ws + 256 + 147456);
  int*      rankof = (int*)(ws + 256 + 2 * 147456);
  ushort_t* Xbf    = (ushort_t*)(ws + 442624);
  ushort_t* W1T    = (ushort_t*)(ws + 8831232);
  ushort_t* W2T    = (ushort_t*)(ws + 84328704);
  ushort_t* He     = (ushort_t*)(ws + 159826176);     // 12288 x 4096 bf16 (+1MB slack)
  int*      nq     = (int*)(ws + 260489472);          // inside He slack
  unsigned int* q1 = (unsigned int*)(ws + 260489536);
  unsigned int* q2 = (unsigned int*)(ws + 260489536 + 16384);
  float*    ybuf   = (float*)(ws + 261538048);

  hipMemsetAsync(cnt, 0, 64, stream);
  gate_kernel<<<T_TOK, 64, 0, stream>>>(x, Wg, cnt, tok, wof, rankof);
  scan_kernel<<<1, 64, 0, stream>>>(cnt, base);
  build_queue_kernel<<<9, 256, 0, stream>>>(cnt, q1, q2, nq);
  cvt_x_kernel<<<2048, 256, 0, stream>>>(x, Xbf);
  tcvt_kernel<<<dim3(64, 16, 8), 256, 0, stream>>>(W1, W1T, 1024, 4096);
  tcvt_kernel<<<dim3(16, 64, 8), 256, 0, stream>>>(W2, W2T, 4096, 1024);
  tcvt_kernel<<<dim3(64, 16, 1), 256, 0, stream>>>(Ws1, W1T + 8L * ESTRIDE, 1024, 4096);
  tcvt_kernel<<<dim3(16, 64, 1), 256, 0, stream>>>(Ws2, W2T + 8L * ESTRIDE, 4096, 1024);
  gemm_kernel<1024, 4096, 1><<<2048, 256, 0, stream>>>(
      Xbf, W1T, b1, bs1, cnt, base, tok, wof, rankof, q1, nq, He, ybuf, out);
  gemm_kernel<4096, 1024, 2><<<2048, 256, 0, stream>>>(
      He, W2T, b2, bs2, cnt, base, tok, wof, rankof, q2, nq, He, ybuf, out);
  final_add_kernel<<<4096, 256, 0, stream>>>(out, ybuf);
}

// Round 6
// 592.534 us; speedup vs baseline: 5.3460x; 5.3460x over previous
//
#include <hip/hip_runtime.h>
#include <hip/hip_bf16.h>

typedef unsigned short ushort_t;
typedef __attribute__((ext_vector_type(4))) float f32x4;
typedef __attribute__((ext_vector_type(8))) short bf16x8;
typedef __attribute__((ext_vector_type(8))) unsigned short us8;

#define T_TOK 4096
#define D_DIM 1024
#define FF_DIM 4096
#define NE 8
#define ESTRIDE 4194304L  // 4096*1024 elements per expert weight matrix

__device__ __forceinline__ unsigned short f2bf(float f) {
  __hip_bfloat16 h = __float2bfloat16(f);
  return __builtin_bit_cast(unsigned short, h);
}
__device__ __forceinline__ float gelu_f(float v) {
  return 0.5f * v * (1.0f + erff(v * 0.70710678118654752440f));
}

// ---------------- gating: logits -> softmax top2 -> expert lists -------------
__global__ void gate_kernel(const float* __restrict__ x, const float* __restrict__ Wg,
                            int* __restrict__ cnt, int* __restrict__ tok,
                            float* __restrict__ wof, int* __restrict__ rankof) {
  const int t = blockIdx.x;
  const int lane = threadIdx.x;  // 64 threads = 1 wave
  const float* xr = x + (long)t * D_DIM;
  float acc[NE];
#pragma unroll
  for (int e = 0; e < NE; e++) acc[e] = 0.f;
#pragma unroll
  for (int i = 0; i < 16; i++) {
    int d = i * 64 + lane;
    float xv = xr[d];
    const float* wr = Wg + d * NE;
#pragma unroll
    for (int e = 0; e < NE; e++) acc[e] += xv * wr[e];
  }
#pragma unroll
  for (int off = 32; off > 0; off >>= 1) {
#pragma unroll
    for (int e = 0; e < NE; e++) acc[e] += __shfl_xor(acc[e], off, 64);
  }
  if (lane == 0) {
    int i0 = 0;
#pragma unroll
    for (int e = 1; e < NE; e++) if (acc[e] > acc[i0]) i0 = e;
    int i1 = -1;
#pragma unroll
    for (int e = 0; e < NE; e++) {
      if (e == i0) continue;
      if (i1 < 0 || acc[e] > acc[i1]) i1 = e;
    }
    float e1 = expf(acc[i1] - acc[i0]);
    float w0 = 1.f / (1.f + e1);
    float w1 = e1 * w0;
    int s0 = atomicAdd(&cnt[i0], 1);
    tok[i0 * T_TOK + s0] = t; wof[i0 * T_TOK + s0] = w0; rankof[i0 * T_TOK + s0] = 0;
    int s1 = atomicAdd(&cnt[i1], 1);
    tok[i1 * T_TOK + s1] = t; wof[i1 * T_TOK + s1] = w1; rankof[i1 * T_TOK + s1] = 1;
    tok[8 * T_TOK + t] = t; wof[8 * T_TOK + t] = 1.f; rankof[8 * T_TOK + t] = 0;
  }
}

__global__ void scan_kernel(int* cnt, int* base) {
  if (threadIdx.x == 0 && blockIdx.x == 0) {
    int s = 0;
    for (int e = 0; e < NE; e++) { base[e] = s; s += cnt[e]; }
    base[8] = s;      // always 8192
    cnt[8] = T_TOK;   // shared pseudo-expert gets all tokens
  }
}

// ---------------- build work-item queues (no dead blocks) -------------------
// m-tile = 256 rows. q1: (e, my, nx<32); q2: (e, my, nx<8). Ordered (e,my,nx)
// so consecutive blocks share A-panels. nq[0]=|q1|, nq[1]=|q2|.
__global__ void build_queue_kernel(const int* __restrict__ cnt,
                                   unsigned int* __restrict__ q1,
                                   unsigned int* __restrict__ q2,
                                   int* __restrict__ nq) {
  const int e = blockIdx.x;  // 9 blocks
  int off1 = 0, off2 = 0, tot1 = 0, tot2 = 0, mym = 0;
  for (int i = 0; i < 9; i++) {
    int c = (i == 8) ? T_TOK : cnt[i];
    int m = (c + 255) >> 8;
    if (i < e) { off1 += m * 32; off2 += m * 8; }
    if (i == e) mym = m;
    tot1 += m * 32; tot2 += m * 8;
  }
  for (int i = threadIdx.x; i < mym * 32; i += 256) {
    int my = i >> 5, nx = i & 31;
    q1[off1 + i] = ((unsigned)e << 16) | ((unsigned)my << 8) | (unsigned)nx;
  }
  for (int i = threadIdx.x; i < mym * 8; i += 256) {
    int my = i >> 3, nx = i & 7;
    q2[off2 + i] = ((unsigned)e << 16) | ((unsigned)my << 8) | (unsigned)nx;
  }
  if (e == 0 && threadIdx.x == 0) { nq[0] = tot1; nq[1] = tot2; }
}

// ---------------- fp32 -> bf16 convert (x) ----------------------------------
__global__ void cvt_x_kernel(const float* __restrict__ src, ushort_t* __restrict__ dst) {
  long i = ((long)blockIdx.x * 256 + threadIdx.x) * 8;
  float4 v0 = *(const float4*)(src + i);
  float4 v1 = *(const float4*)(src + i + 4);
  us8 o;
  o[0] = f2bf(v0.x); o[1] = f2bf(v0.y); o[2] = f2bf(v0.z); o[3] = f2bf(v0.w);
  o[4] = f2bf(v1.x); o[5] = f2bf(v1.y); o[6] = f2bf(v1.z); o[7] = f2bf(v1.w);
  *(us8*)(dst + i) = o;
}

// ---------------- fp32 [R][C] -> bf16 [C][R] transpose-convert --------------
__global__ void tcvt_kernel(const float* __restrict__ src, ushort_t* __restrict__ dst,
                            int R, int C) {
  src += (long)blockIdx.z * R * C;
  dst += (long)blockIdx.z * R * C;
  const int r0 = blockIdx.y * 64, c0 = blockIdx.x * 64;
  __shared__ ushort_t tile[64][72];
  const int t = threadIdx.x;
#pragma unroll
  for (int i = 0; i < 4; i++) {
    int lin = t + i * 256;
    int r = lin >> 4;
    int c = (lin & 15) * 4;
    float4 v = *(const float4*)(src + (long)(r0 + r) * C + c0 + c);
    tile[c + 0][r] = f2bf(v.x);
    tile[c + 1][r] = f2bf(v.y);
    tile[c + 2][r] = f2bf(v.z);
    tile[c + 3][r] = f2bf(v.w);
  }
  __syncthreads();
#pragma unroll
  for (int i = 0; i < 2; i++) {
    int lin = t + i * 256;
    int cc = lin >> 3, rp = lin & 7;
    us8 v = *(const us8*)&tile[cc][rp * 8];
    *(us8*)(dst + (long)(c0 + cc) * R + r0 + rp * 8) = v;
  }
}

// ---------------- GEMM: 256x128 tile, 4 waves, wave=128x64 (acc[8][4]) ------
// Persistent queue blocks, BK=32, single-sync double buffer (48 KiB LDS),
// conflict-free XOR swizzle (r3-proven: stored slot = kc ^ ((row>>1)&3),
// inverse applied on per-lane GLOBAL source, LDS dest linear; read uses
// swk = (lg ^ ((lr>>1)&3))<<4). 43 FLOP per LDS byte (vs 32 before).
// __launch_bounds__(256,2): ~200 total regs/wave -> 2 blocks/CU.
// PHASE 1: He = gelu(gather(Xbf) @ W1T^T + b1)   (K=1024, N=4096)
// PHASE 2: ybuf/out = route(He @ W2T^T + b2)     (K=4096, N=1024)
template <int K, int N, int PHASE>
__global__ __launch_bounds__(256, 2) void gemm_kernel(
    const ushort_t* __restrict__ Abase, const ushort_t* __restrict__ WT,
    const float* __restrict__ bias_e, const float* __restrict__ bias_s,
    const int* __restrict__ cnt, const int* __restrict__ base,
    const int* __restrict__ tok, const float* __restrict__ wof,
    const int* __restrict__ rankof,
    const unsigned int* __restrict__ q, const int* __restrict__ nq_all,
    ushort_t* __restrict__ He, float* __restrict__ ybuf, float* __restrict__ out) {
  const int nq = nq_all[PHASE - 1];
  const int tid = threadIdx.x;
  const int w = tid >> 6, lane = tid & 63;
  const int wm = w >> 1, wn = w & 1;      // wave tile: rows wm*128, cols wn*64
  const int lr = lane & 15, lg = lane >> 4;
  const int swk = (lg ^ ((lr >> 1) & 3)) << 4;  // read-side swizzle byte off

  __shared__ ushort_t lds_u[2 * 12288];  // 2 x (A 16KB + B 8KB) = 48 KiB
  char* const lds = (char*)lds_u;

  // staging geometry: thread covers row i*64 + (tid>>2), stored 16B-slot tid&3,
  // global 8-elem chunk kcg = (tid&3) ^ ((tid>>3)&3)  [inverse swizzle]
  const int srow = tid >> 2;
  const int kcg = (tid & 3) ^ ((tid >> 3) & 3);

  for (int it = blockIdx.x; it < nq; it += gridDim.x) {
    const unsigned int item = q[it];
    const int e = item >> 16;
    const int m0 = ((item >> 8) & 0xff) * 256;
    const int n0 = (item & 0xff) * 128;
    const int count = cnt[e];

    const ushort_t* pA[4];
    const ushort_t* pB[2];
#pragma unroll
    for (int i = 0; i < 4; i++) {
      int rr = m0 + i * 64 + srow;
      int rc = (rr < count) ? rr : 0;  // clamp OOB rows
      long arow;
      if (PHASE == 1) arow = tok[e * T_TOK + rc];
      else            arow = (long)base[e] + rc;
      pA[i] = Abase + arow * (long)K + kcg * 8;
    }
#pragma unroll
    for (int i = 0; i < 2; i++)
      pB[i] = WT + (long)e * ESTRIDE + (long)(n0 + i * 64 + srow) * K + kcg * 8;

#define STAGE(buf_, kk_)                                                         \
    do {                                                                         \
      char* d_ = lds + (buf_) * 24576 + tid * 16;                                \
      _Pragma("unroll")                                                          \
      for (int i_ = 0; i_ < 4; i_++)                                             \
        __builtin_amdgcn_global_load_lds(                                        \
            (const __attribute__((address_space(1))) void*)(pA[i_] + (kk_)),     \
            (__attribute__((address_space(3))) void*)(d_ + i_ * 4096), 16, 0, 0);\
      _Pragma("unroll")                                                          \
      for (int i_ = 0; i_ < 2; i_++)                                             \
        __builtin_amdgcn_global_load_lds(                                        \
            (const __attribute__((address_space(1))) void*)(pB[i_] + (kk_)),     \
            (__attribute__((address_space(3))) void*)(d_ + 16384 + i_ * 4096),   \
            16, 0, 0);                                                           \
    } while (0)

    f32x4 acc[8][4] = {};

    STAGE(0, 0);
    __syncthreads();

    int cur = 0;
    for (int k0 = 0; k0 < K; k0 += 32) {
      if (k0 + 32 < K) STAGE(cur ^ 1, k0 + 32);  // prefetch overlaps reads+MFMA

      const char* aB = lds + cur * 24576;
      const char* bB = aB + 16384;
      bf16x8 av[8], bv[4];
#pragma unroll
      for (int m = 0; m < 8; m++)
        av[m] = *(const bf16x8*)(aB + (wm * 128 + m * 16 + lr) * 64 + swk);
#pragma unroll
      for (int n = 0; n < 4; n++)
        bv[n] = *(const bf16x8*)(bB + (wn * 64 + n * 16 + lr) * 64 + swk);
#pragma unroll
      for (int m = 0; m < 8; m++)
#pragma unroll
        for (int n = 0; n < 4; n++)
          acc[m][n] = __builtin_amdgcn_mfma_f32_16x16x32_bf16(av[m], bv[n], acc[m][n], 0, 0, 0);

      __syncthreads();  // drains prefetch vmcnt + protects buffer reuse
      cur ^= 1;
    }
#undef STAGE

    const float* bias = (e == NE) ? bias_s : (bias_e + (long)e * N);
#pragma unroll
    for (int m = 0; m < 8; m++) {
#pragma unroll
      for (int j = 0; j < 4; j++) {
        int rloc = wm * 128 + m * 16 + lg * 4 + j;  // D row = (lane>>4)*4 + reg
        int rr = m0 + rloc;
        if (rr >= count) continue;
        if (PHASE == 1) {
          long orow = (long)base[e] + rr;
#pragma unroll
          for (int n = 0; n < 4; n++) {
            int col = n0 + wn * 64 + n * 16 + lr;  // D col = lane&15
            float v = acc[m][n][j] + bias[col];
            He[orow * FF_DIM + col] = f2bf(gelu_f(v));
          }
        } else {
          int tt = tok[e * T_TOK + rr];
          if (e == NE) {  // shared FFN -> d_out directly
#pragma unroll
            for (int n = 0; n < 4; n++) {
              int col = n0 + wn * 64 + n * 16 + lr;
              out[(long)tt * D_DIM + col] = acc[m][n][j] + bias[col];
            }
          } else {
            float wgt = wof[e * T_TOK + rr];
            int rk = rankof[e * T_TOK + rr];
            float* dst = ybuf + (long)rk * ((long)T_TOK * D_DIM) + (long)tt * D_DIM;
#pragma unroll
            for (int n = 0; n < 4; n++) {
              int col = n0 + wn * 64 + n * 16 + lr;
              dst[col] = wgt * (acc[m][n][j] + bias[col]);
            }
          }
        }
      }
    }
    // K-loop ended with __syncthreads(); epilogue touches no LDS -> next
    // item's STAGE (after its own position in program order) is safe.
  }
}

// ---------------- final: out += y_rank0 + y_rank1 ---------------------------
__global__ void final_add_kernel(float* __restrict__ out, const float* __restrict__ ybuf) {
  long i = ((long)blockIdx.x * 256 + threadIdx.x) * 4;
  float4 a = *(const float4*)(out + i);
  float4 b = *(const float4*)(ybuf + i);
  float4 c = *(const float4*)(ybuf + (long)T_TOK * D_DIM + i);
  a.x += b.x + c.x; a.y += b.y + c.y; a.z += b.z + c.z; a.w += b.w + c.w;
  *(float4*)(out + i) = a;
}

extern "C" void kernel_launch(void* const* d_in, const int* in_sizes, int n_in,
                              void* d_out, int out_size, void* d_ws, size_t ws_size,
                              hipStream_t stream) {
  (void)in_sizes; (void)n_in; (void)out_size; (void)ws_size;
  const float* x   = (const float*)d_in[0];
  const float* Wg  = (const float*)d_in[1];
  const float* W1  = (const float*)d_in[2];
  const float* b1  = (const float*)d_in[3];
  const float* W2  = (const float*)d_in[4];
  const float* b2  = (const float*)d_in[5];
  const float* Ws1 = (const float*)d_in[6];
  const float* bs1 = (const float*)d_in[7];
  const float* Ws2 = (const float*)d_in[8];
  const float* bs2 = (const float*)d_in[9];
  float* out = (float*)d_out;

  char* ws = (char*)d_ws;
  int*      cnt    = (int*)(ws + 0);
  int*      base   = (int*)(ws + 64);
  int*      tok    = (int*)(ws + 256);
  float*    wof    = (float*)(ws + 256 + 147456);
  int*      rankof = (int*)(ws + 256 + 2 * 147456);
  ushort_t* Xbf    = (ushort_t*)(ws + 442624);
  ushort_t* W1T    = (ushort_t*)(ws + 8831232);
  ushort_t* W2T    = (ushort_t*)(ws + 84328704);
  ushort_t* He     = (ushort_t*)(ws + 159826176);     // 12288 x 4096 bf16
  int*      nq     = (int*)(ws + 260489472);
  unsigned int* q1 = (unsigned int*)(ws + 260489536);          // <= 8 KB used
  unsigned int* q2 = (unsigned int*)(ws + 260489536 + 32768);  // <= 2 KB used
  float*    ybuf   = (float*)(ws + 261538048);

  hipMemsetAsync(cnt, 0, 64, stream);
  gate_kernel<<<T_TOK, 64, 0, stream>>>(x, Wg, cnt, tok, wof, rankof);
  scan_kernel<<<1, 64, 0, stream>>>(cnt, base);
  build_queue_kernel<<<9, 256, 0, stream>>>(cnt, q1, q2, nq);
  cvt_x_kernel<<<2048, 256, 0, stream>>>(x, Xbf);
  tcvt_kernel<<<dim3(64, 16, 8), 256, 0, stream>>>(W1, W1T, 1024, 4096);
  tcvt_kernel<<<dim3(16, 64, 8), 256, 0, stream>>>(W2, W2T, 4096, 1024);
  tcvt_kernel<<<dim3(64, 16, 1), 256, 0, stream>>>(Ws1, W1T + 8L * ESTRIDE, 1024, 4096);
  tcvt_kernel<<<dim3(16, 64, 1), 256, 0, stream>>>(Ws2, W2T + 8L * ESTRIDE, 4096, 1024);
  gemm_kernel<1024, 4096, 1><<<512, 256, 0, stream>>>(
      Xbf, W1T, b1, bs1, cnt, base, tok, wof, rankof, q1, nq, He, ybuf, out);
  gemm_kernel<4096, 1024, 2><<<512, 256, 0, stream>>>(
      He, W2T, b2, bs2, cnt, base, tok, wof, rankof, q2, nq, He, ybuf, out);
  final_add_kernel<<<4096, 256, 0, stream>>>(out, ybuf);
}